// Round 20
// baseline (190.702 us; speedup 1.0000x reference)
//
#include <hip/hip_runtime.h>

// Masked self-attention, B=4 T=2048 C=1024 (single head, head dim = C).
// Banked r18 config (181.4 µs) + QK-proj swapped to the 2-phase engine:
//  gemm8  : 256x256 / BK=64 / 8-wave deep-staged pipelined (scores, PV).
//           EPI 5 = split-K2 partial (PV), 6 = scores exp+rowsum (tri).
//  gemm2ph: 256x128 2-phase, counted vmcnt(4)/(2).
//           EPI 2 = out-proj f32+bias[col], 3 = QK-proj bf16+bias[col]
//           (512 blocks = 2 rounds; per-round == out-proj's measured 13 µs),
//           4 = Vt-proj bf16+bias[row].
// LDS swizzle: 16B-slot ^= (row&7), both-sides. T1 XCD-bijective swizzle.
// Softmax fused in scores epilogue; reduce_pv2 divides by rowsum.
// Pipeline: prep | QK(2ph) | Vt | scores | PV splitK2 | reduce2 | out.

typedef __attribute__((ext_vector_type(8))) short short8;
typedef __attribute__((ext_vector_type(4))) float f32x4;
typedef __attribute__((ext_vector_type(4))) unsigned short us4;
typedef __attribute__((ext_vector_type(8))) unsigned short us8;
typedef __attribute__((ext_vector_type(4))) float fl4;

__device__ __forceinline__ unsigned short f2b(float f) {
  unsigned int u = __builtin_bit_cast(unsigned int, f);
  u += 0x7fffu + ((u >> 16) & 1u);   // round-to-nearest-even
  return (unsigned short)(u >> 16);
}
__device__ __forceinline__ float b2f(unsigned short h) {
  unsigned int u = ((unsigned int)h) << 16;
  return __builtin_bit_cast(float, u);
}

// ------- prep (grid-stride): converts + bias packing + rowsum zero -------
__global__ __launch_bounds__(256) void prep_kernel(
    const float* __restrict__ x,
    const float* __restrict__ Wq, const float* __restrict__ Wk,
    const float* __restrict__ Wv, const float* __restrict__ Wo,
    const float* __restrict__ bq, const float* __restrict__ bk,
    const float* __restrict__ bv, const float* __restrict__ bo,
    unsigned short* __restrict__ xb, unsigned short* __restrict__ Wqkvb,
    unsigned short* __restrict__ Wob, float* __restrict__ bws,
    float* __restrict__ rows) {
  const unsigned stride = gridDim.x * 256u;
  for (unsigned i = blockIdx.x * 256u + threadIdx.x; i < 3148800u; i += stride) {
    if (i < 2097152u) {
      fl4 f = *(const fl4*)&x[(size_t)i << 2];
      us4 o;
#pragma unroll
      for (int j = 0; j < 4; ++j) o[j] = f2b(f[j]);
      *(us4*)&xb[(size_t)i << 2] = o;
    } else if (i < 3145728u) {
      const unsigned k = i - 2097152u;
      const int w = k >> 18;
      const unsigned idx = k & 262143u;
      const float* s = w == 0 ? Wq : w == 1 ? Wk : w == 2 ? Wv : Wo;
      unsigned short* d = w < 3 ? Wqkvb + (size_t)w * 1024 * 1024 : Wob;
      fl4 f = *(const fl4*)&s[(size_t)idx << 2];
      us4 o;
#pragma unroll
      for (int j = 0; j < 4; ++j) o[j] = f2b(f[j]);
      *(us4*)&d[(size_t)idx << 2] = o;
    } else if (i < 3146752u) {
      const unsigned j = i - 3145728u;
      const int sel = j >> 8;
      const unsigned within = j & 255u;
      const float* p = sel == 0 ? bq : sel == 1 ? bk : sel == 2 ? bv : bo;
      *(fl4*)&bws[(size_t)j << 2] = *(const fl4*)&p[(size_t)within << 2];
    } else {
      const unsigned j = i - 3146752u;
      *(fl4*)&rows[(size_t)j << 2] = fl4{0.f, 0.f, 0.f, 0.f};
    }
  }
}

#define RD_A(dst, basep)                                                   \
  _Pragma("unroll") for (int mi = 0; mi < 4; ++mi)                         \
  _Pragma("unroll") for (int ks = 0; ks < 2; ++ks)                         \
      dst[mi][ks] = *(const short8*)((basep) + offA[mi][ks]);

#define RD_B(dst, basep)                                                   \
  _Pragma("unroll") for (int nj = 0; nj < 2; ++nj)                         \
  _Pragma("unroll") for (int ks = 0; ks < 2; ++ks)                         \
      dst[nj][ks] = *(const short8*)((basep) + offB[nj][ks]);

#define MFMA16(AF, BF, MI0, NJ0)                                           \
  __builtin_amdgcn_s_setprio(1);                                           \
  _Pragma("unroll") for (int ks = 0; ks < 2; ++ks)                         \
  _Pragma("unroll") for (int mi = 0; mi < 4; ++mi)                         \
  _Pragma("unroll") for (int nj = 0; nj < 2; ++nj)                         \
      acc[(MI0) + mi][(NJ0) + nj] = __builtin_amdgcn_mfma_f32_16x16x32_bf16( \
          AF[mi][ks], BF[nj][ks], acc[(MI0) + mi][(NJ0) + nj], 0, 0, 0);   \
  __builtin_amdgcn_s_setprio(0);

// Deep-staged 8-barrier K-loop (T4: +2-tile stage lead, one vmcnt(8)/tile).
#define KLOOP_BODY                                                         \
  stA(0, 0, 0); stB(0, 0, 0); stA(0, 1, 0); stB(0, 1, 0);                  \
  stA(1, 0, 1); stB(1, 0, 1); stA(1, 1, 1); stB(1, 1, 1);                  \
  asm volatile("s_waitcnt vmcnt(8)" ::: "memory");                         \
  __builtin_amdgcn_s_barrier();                                            \
  for (int t = 0; t < nt; ++t) {                                           \
    const int buf = t & 1;                                                 \
    const char* Ab0 = (const char*)&lA[buf][0][0];                         \
    const char* Ab1 = (const char*)&lA[buf][1][0];                         \
    const char* Bb0 = (const char*)&lB[buf][0][0];                         \
    const char* Bb1 = (const char*)&lB[buf][1][0];                         \
    short8 a0[4][2], a1[4][2], b0[2][2], b1[2][2];                         \
    RD_A(a0, Ab0);                                                         \
    RD_B(b0, Bb0);                                                         \
    __builtin_amdgcn_s_barrier();                                          \
    MFMA16(a0, b0, 0, 0);                                                  \
    __builtin_amdgcn_s_barrier();                                          \
    RD_A(a1, Ab1);                                                         \
    stA(buf, 0, t + 2);                                                    \
    stB(buf, 0, t + 2);                                                    \
    __builtin_amdgcn_s_barrier();                                          \
    MFMA16(a1, b0, 4, 0);                                                  \
    __builtin_amdgcn_s_barrier();                                          \
    RD_B(b1, Bb1);                                                         \
    stA(buf, 1, t + 2);                                                    \
    __builtin_amdgcn_s_barrier();                                          \
    MFMA16(a1, b1, 4, 2);                                                  \
    __builtin_amdgcn_s_barrier();                                          \
    stB(buf, 1, t + 2);                                                    \
    asm volatile("s_waitcnt vmcnt(8)" ::: "memory");                       \
    __builtin_amdgcn_s_barrier();                                          \
    MFMA16(a0, b1, 0, 2);                                                  \
    __builtin_amdgcn_s_barrier();                                          \
  }                                                                        \
  asm volatile("s_waitcnt vmcnt(0)" ::: "memory");

// ---------------- gemm8: 256x256 deep-staged pipelined ----------------
// EPI: 5 = split-K2 bf16 partial (half -> P0|P1)
//      6 = scores: bf16 exp(v*scale) causal-masked + rowsum atomics
template<int EPI, bool SPLIT2, bool SKIP_UPPER>
__global__ __launch_bounds__(512, 2)
void gemm8(const unsigned short* __restrict__ A, const unsigned short* __restrict__ B,
           void* __restrict__ Cout, const float* __restrict__ bias,
           float* __restrict__ rows, float scale, int K,
           int lda, int ldb, int ldc,
           long long sAz, long long sBz, long long sCz)
{
  const int gx = gridDim.x;
  const int nwg = gx * gridDim.y;
  int flat = blockIdx.y * gx + blockIdx.x;
  { const int q = nwg >> 3, r = nwg & 7, xc = flat & 7, i = flat >> 3;
    flat = (xc < r ? xc * (q + 1) : r * (q + 1) + (xc - r) * q) + i; }
  const int m0 = (flat / gx) << 8;
  const int n0 = (flat % gx) << 8;
  if (SKIP_UPPER && n0 > m0 + 255) return;   // fully-masked score block
  const int zraw = blockIdx.z;
  const int z = SPLIT2 ? (zraw >> 1) : zraw;

  int kBeg = 0, kEnd = K;
  if (SPLIT2) {                        // balanced causal half (PV)
    const int kFull = m0 + 256;
    const int kMid = kFull >> 1;
    kBeg = (zraw & 1) ? kMid : 0;
    kEnd = (zraw & 1) ? kFull : kMid;
  }
  const int nt = (kEnd - kBeg) >> 6;

  __shared__ unsigned short lA[2][2][8192];
  __shared__ unsigned short lB[2][2][8192];

  const int tid = threadIdx.x, lane = tid & 63, wid = tid >> 6;
  const int wm = wid >> 2, wn = wid & 3;
  const int fr = lane & 15, kg = lane >> 4;

  const unsigned short* Ab = A + (size_t)z * sAz;
  const unsigned short* Bb = B + (size_t)z * sBz;

  const int xorv = (fr & 7) << 4;
  int offA[4][2], offB[2][2];
#pragma unroll
  for (int mi = 0; mi < 4; ++mi)
#pragma unroll
    for (int ks = 0; ks < 2; ++ks)
      offA[mi][ks] = ((wm << 6) + (mi << 4) + fr) * 128 + (((ks << 6) + (kg << 4)) ^ xorv);
#pragma unroll
  for (int nj = 0; nj < 2; ++nj)
#pragma unroll
    for (int ks = 0; ks < 2; ++ks)
      offB[nj][ks] = ((wn << 5) + (nj << 4) + fr) * 128 + (((ks << 6) + (kg << 4)) ^ xorv);

  const int srow = tid >> 3;
  const int scol = (((tid & 7) ^ (srow & 7)) << 3);
  const unsigned short* aS = Ab + (size_t)(m0 + srow) * lda + scol + kBeg;
  const unsigned short* bS = Bb + (size_t)(n0 + srow) * ldb + scol + kBeg;

  auto stA = [&](int buf, int h, int tt) {
    int ttc = tt < nt ? tt : nt - 1;
    const unsigned short* s0 = aS + (size_t)(h << 7) * lda + (ttc << 6);
#pragma unroll
    for (int c = 0; c < 2; ++c)
      __builtin_amdgcn_global_load_lds(
          (const __attribute__((address_space(1))) void*)(s0 + (size_t)(c << 6) * lda),
          (__attribute__((address_space(3))) void*)((char*)&lA[buf][h][0] + (c << 13) + (tid << 4)),
          16, 0, 0);
  };
  auto stB = [&](int buf, int h, int tt) {
    int ttc = tt < nt ? tt : nt - 1;
    const unsigned short* s0 = bS + (size_t)(h << 7) * ldb + (ttc << 6);
#pragma unroll
    for (int c = 0; c < 2; ++c)
      __builtin_amdgcn_global_load_lds(
          (const __attribute__((address_space(1))) void*)(s0 + (size_t)(c << 6) * ldb),
          (__attribute__((address_space(3))) void*)((char*)&lB[buf][h][0] + (c << 13) + (tid << 4)),
          16, 0, 0);
  };

  f32x4 acc[8][4];
#pragma unroll
  for (int i = 0; i < 8; ++i)
#pragma unroll
    for (int j = 0; j < 4; ++j) acc[i][j] = f32x4{0.f, 0.f, 0.f, 0.f};

  KLOOP_BODY

  if (EPI == 6) {
    unsigned short* Ch = (unsigned short*)Cout + (size_t)z * sCz;
#pragma unroll
    for (int mig = 0; mig < 8; ++mig) {
      const int row = m0 + (mig >> 2) * 128 + wm * 64 + (mig & 3) * 16 + (kg << 2);
#pragma unroll
      for (int jj = 0; jj < 4; ++jj) {
        const int r = row + jj;
        float rs = 0.f;
#pragma unroll
        for (int njg = 0; njg < 4; ++njg) {
          const int col = n0 + (njg >> 1) * 128 + wn * 32 + (njg & 1) * 16 + fr;
          const float ee = (col <= r) ? __expf(acc[mig][njg][jj] * scale) : 0.f;
          rs += ee;
          Ch[(size_t)r * ldc + col] = f2b(ee);
        }
#pragma unroll
        for (int mk = 1; mk <= 8; mk <<= 1) rs += __shfl_xor(rs, mk, 64);
        if (fr == 0) atomicAdd(&rows[z * 2048 + r], rs);
      }
    }
    return;
  }
#pragma unroll
  for (int mig = 0; mig < 8; ++mig)
#pragma unroll
    for (int njg = 0; njg < 4; ++njg) {
      const int row = m0 + (mig >> 2) * 128 + wm * 64 + (mig & 3) * 16 + (kg << 2);
      const int col = n0 + (njg >> 1) * 128 + wn * 32 + (njg & 1) * 16 + fr;
      f32x4 v = acc[mig][njg];
      // EPI == 5: split-K2 partial; half selects P0|P1
      unsigned short* Ch = (unsigned short*)Cout +
          (size_t)(zraw & 1) * 8388608 + (size_t)z * sCz;
#pragma unroll
      for (int jj = 0; jj < 4; ++jj)
        Ch[(size_t)(row + jj) * ldc + col] = f2b(v[jj]);
    }
}

// ---------------- gemm2ph: 256x128 2-phase, 4-barrier ----------------
// EPI: 2 = f32 + bias[col] (out-proj)   3 = bf16 + bias[col] (QK-proj)
//      4 = bf16 + bias[row] (Vt-proj)
template<int EPI>
__global__ __launch_bounds__(512, 2)
void gemm2ph(const unsigned short* __restrict__ A, const unsigned short* __restrict__ B,
             void* __restrict__ Cout, const float* __restrict__ bias,
             int K, int lda, int ldb, int ldc)
{
  const int gx = gridDim.x;
  const int nwg = gx * gridDim.y;
  int flat = blockIdx.y * gx + blockIdx.x;
  { const int q = nwg >> 3, r = nwg & 7, xc = flat & 7, i = flat >> 3;
    flat = (xc < r ? xc * (q + 1) : r * (q + 1) + (xc - r) * q) + i; }
  const int m0 = (flat / gx) << 8;
  const int n0 = (flat % gx) << 7;
  const int nt = K >> 6;

  __shared__ unsigned short lA[2][2][8192];   // 64 KB
  __shared__ unsigned short lB[2][8192];      // 32 KB

  const int tid = threadIdx.x, lane = tid & 63, wid = tid >> 6;
  const int wm = wid >> 2, wn = wid & 3;
  const int fr = lane & 15, kg = lane >> 4;

  const int xorv = (fr & 7) << 4;
  int offA[4][2], offB[2][2];
#pragma unroll
  for (int mi = 0; mi < 4; ++mi)
#pragma unroll
    for (int ks = 0; ks < 2; ++ks)
      offA[mi][ks] = ((wm << 6) + (mi << 4) + fr) * 128 + (((ks << 6) + (kg << 4)) ^ xorv);
#pragma unroll
  for (int nj = 0; nj < 2; ++nj)
#pragma unroll
    for (int ks = 0; ks < 2; ++ks)
      offB[nj][ks] = ((wn << 5) + (nj << 4) + fr) * 128 + (((ks << 6) + (kg << 4)) ^ xorv);

  const int srow = tid >> 3;
  const int scol = (((tid & 7) ^ (srow & 7)) << 3);
  const unsigned short* aS = A + (size_t)(m0 + srow) * lda + scol;
  const unsigned short* bS = B + (size_t)(n0 + srow) * ldb + scol;

  auto stA = [&](int buf, int h, int tt) {
    int ttc = tt < nt ? tt : nt - 1;
    const unsigned short* s0 = aS + (size_t)(h << 7) * lda + (ttc << 6);
#pragma unroll
    for (int c = 0; c < 2; ++c)
      __builtin_amdgcn_global_load_lds(
          (const __attribute__((address_space(1))) void*)(s0 + (size_t)(c << 6) * lda),
          (__attribute__((address_space(3))) void*)((char*)&lA[buf][h][0] + (c << 13) + (tid << 4)),
          16, 0, 0);
  };
  auto stB = [&](int buf, int tt) {
    int ttc = tt < nt ? tt : nt - 1;
    const unsigned short* s0 = bS + (ttc << 6);
#pragma unroll
    for (int c = 0; c < 2; ++c)
      __builtin_amdgcn_global_load_lds(
          (const __attribute__((address_space(1))) void*)(s0 + (size_t)(c << 6) * ldb),
          (__attribute__((address_space(3))) void*)((char*)&lB[buf][0] + (c << 13) + (tid << 4)),
          16, 0, 0);
  };

  f32x4 acc[8][2];
#pragma unroll
  for (int i = 0; i < 8; ++i)
#pragma unroll
    for (int j = 0; j < 2; ++j) acc[i][j] = f32x4{0.f, 0.f, 0.f, 0.f};

  stB(0, 0); stA(0, 0, 0); stA(0, 1, 0);
  asm volatile("s_waitcnt vmcnt(2)" ::: "memory");
  __builtin_amdgcn_s_barrier();

  for (int t = 0; t < nt; ++t) {
    const int buf = t & 1, nbuf = buf ^ 1;
    const char* Ab0 = (const char*)&lA[buf][0][0];
    const char* Ab1 = (const char*)&lA[buf][1][0];
    const char* Bbp = (const char*)&lB[buf][0];

    short8 a0[4][2], a1[4][2], b0[2][2];

    RD_A(a0, Ab0);
    RD_B(b0, Bbp);
    stB(nbuf, t + 1); stA(nbuf, 0, t + 1);
    asm volatile("s_waitcnt vmcnt(4)" ::: "memory");
    __builtin_amdgcn_s_barrier();
    MFMA16(a0, b0, 0, 0);
    __builtin_amdgcn_s_barrier();

    RD_A(a1, Ab1);
    stA(nbuf, 1, t + 1);
    asm volatile("s_waitcnt vmcnt(2)" ::: "memory");
    __builtin_amdgcn_s_barrier();
    MFMA16(a1, b0, 4, 0);
    __builtin_amdgcn_s_barrier();
  }
  asm volatile("s_waitcnt vmcnt(0)" ::: "memory");

#pragma unroll
  for (int mig = 0; mig < 8; ++mig)
#pragma unroll
    for (int njg = 0; njg < 2; ++njg) {
      const int row = m0 + (mig >> 2) * 128 + wm * 64 + (mig & 3) * 16 + (kg << 2);
      const int col = n0 + wn * 32 + njg * 16 + fr;
      f32x4 v = acc[mig][njg];
      if (EPI == 2) {
        float* Cf = (float*)Cout;
        const float bb = bias[col];
#pragma unroll
        for (int jj = 0; jj < 4; ++jj)
          Cf[(size_t)(row + jj) * ldc + col] = v[jj] + bb;
      } else if (EPI == 3) {   // QK-proj: bf16 + bias[col]
        unsigned short* Ch = (unsigned short*)Cout;
        const float bb = bias[col];
#pragma unroll
        for (int jj = 0; jj < 4; ++jj)
          Ch[(size_t)(row + jj) * ldc + col] = f2b(v[jj] + bb);
      } else {   // EPI == 4: bias by row (Vt-proj)
        unsigned short* Ch = (unsigned short*)Cout;
#pragma unroll
        for (int jj = 0; jj < 4; ++jj)
          Ch[(size_t)(row + jj) * ldc + col] = f2b(v[jj] + bias[row + jj]);
      }
    }
}

// ---- split-K2 reduce + normalize (grid-stride): attn = (P0+P1)/rowsum ----
__global__ __launch_bounds__(256)
void reduce_pv2(const unsigned short* __restrict__ p0,
                const unsigned short* __restrict__ p1,
                const float* __restrict__ rows,
                unsigned short* __restrict__ out) {
  const unsigned stride = gridDim.x * 256u;
  for (unsigned g = blockIdx.x * 256u + threadIdx.x; g < 1048576u; g += stride) {
    const size_t i = (size_t)g << 3;
    const float inv = 1.f / rows[i >> 10];
    us8 a = *(const us8*)&p0[i];
    us8 b = *(const us8*)&p1[i];
    us8 o;
#pragma unroll
    for (int j = 0; j < 8; ++j)
      o[j] = f2b((b2f(a[j]) + b2f(b[j])) * inv);
    *(us8*)&out[i] = o;
  }
}

// ---------------- host-side launch ----------------
extern "C" void kernel_launch(void* const* d_in, const int* in_sizes, int n_in,
                              void* d_out, int out_size, void* d_ws, size_t ws_size,
                              hipStream_t stream) {
  (void)in_sizes; (void)n_in; (void)out_size; (void)ws_size;
  const float* x  = (const float*)d_in[0];
  const float* Wq = (const float*)d_in[1];
  const float* bq = (const float*)d_in[2];
  const float* Wk = (const float*)d_in[3];
  const float* bk = (const float*)d_in[4];
  const float* Wv = (const float*)d_in[5];
  const float* bv = (const float*)d_in[6];
  const float* Wo = (const float*)d_in[7];
  const float* bo = (const float*)d_in[8];

  const int B = 4, T = 2048, C = 1024;
  const int M = B * T;                                   // 8192

  unsigned short* xb    = (unsigned short*)d_ws;         // M*C
  unsigned short* Wqkvb = xb    + (size_t)M * C;         // [Wq|Wk|Wv]
  unsigned short* Wob   = Wqkvb + (size_t)3 * C * C;
  unsigned short* QK    = Wob   + (size_t)C * C;         // M*2C [Q|K]; later P0|P1
  unsigned short* Vt    = QK    + (size_t)M * 2 * C;     // [1024][8192]
  unsigned short* S     = Vt    + (size_t)M * C;         // B*T*T e-values
  float*          bws   = (float*)(S + (size_t)B * T * T);
  float*          rowsum= bws + 4096;                    // 8192 f32
  unsigned short* P0    = QK;
  unsigned short* P1    = QK + (size_t)M * C;
  unsigned short* attn  = P0;

  // 1. prep (grid-stride, 2048 blocks)
  prep_kernel<<<2048, 256, 0, stream>>>(x, Wq, Wk, Wv, Wo, bq, bk, bv, bo,
                                        xb, Wqkvb, Wob, bws, rowsum);

  // 2. QK projection (2-phase engine, 512 blocks = 2 full rounds)
  gemm2ph<3><<<dim3(16, 32), 512, 0, stream>>>(
      xb, Wqkvb, QK, bws, C, C, C, 2 * C);

  // 3. Vt = Wv @ x^T + bv[row] (256 blocks, BN=128)
  gemm2ph<4><<<dim3(M / 128, C / 256, 1), 512, 0, stream>>>(
      Wqkvb + (size_t)2 * C * C, xb, Vt, bws + 2 * C, C, C, C, M);

  // 4. scores: S = exp(Q K^T / 32) causal-masked + rowsum atomics
  gemm8<6, false, true><<<dim3(T / 256, T / 256, B), 512, 0, stream>>>(
      QK, QK + C, S, nullptr, rowsum, 0.03125f, C, 2 * C, 2 * C, T,
      (long long)T * 2 * C, (long long)T * 2 * C, (long long)T * T);

  // 5. PV split-K2: partials P0|P1 (z = batch*2 + half), 256 blocks
  gemm8<5, true, false><<<dim3(C / 256, T / 256, 2 * B), 512, 0, stream>>>(
      S, Vt, P0, nullptr, nullptr, 1.f, T, T, M, C,
      (long long)T * T, 2048LL, (long long)T * C);

  // 6. reduce + normalize (grid-stride, 2048 blocks; attn -> P0 in place)
  reduce_pv2<<<2048, 256, 0, stream>>>(P0, P1, rowsum, attn);

  // 7. out = attn Wo^T + bo (f32, 256 blocks BN=128)
  gemm2ph<2><<<dim3(C / 128, M / 256, 1), 512, 0, stream>>>(
      attn, Wob, d_out, bws + 3 * C, C, C, C, C);
}

// Round 21
// 181.907 us; speedup vs baseline: 1.0484x; 1.0484x over previous
//
#include <hip/hip_runtime.h>

// Masked self-attention, B=4 T=2048 C=1024 (single head, head dim = C).
// FINAL BANKED CONFIGURATION (rounds 18/19, measured 181.4-181.7 µs, 3x).
//  gemm8  : 256x256 / BK=64 / 8-wave deep-staged pipelined (+2-tile stage
//           lead into current buf, one vmcnt(8)/K-tile, 2 barriers/phase).
//           EPI 3 = bf16+bias[col] (QK), 5 = split-K2 partial (PV),
//           6 = scores exp+rowsum (tri early-exit).
//  gemm2ph: 256x128 2-phase (Vt-proj bf16+bias[row]; out-proj f32+bias[col]).
// LDS swizzle: 16B-slot ^= (row&7), both-sides. T1 XCD-bijective swizzle.
// Softmax fused in scores epilogue; reduce_pv2 divides by rowsum.
// prep/reduce: 2048-block grid-stride.
// Pipeline: prep | QK | Vt | scores | PV splitK2 | reduce2 | out.

typedef __attribute__((ext_vector_type(8))) short short8;
typedef __attribute__((ext_vector_type(4))) float f32x4;
typedef __attribute__((ext_vector_type(4))) unsigned short us4;
typedef __attribute__((ext_vector_type(8))) unsigned short us8;
typedef __attribute__((ext_vector_type(4))) float fl4;

__device__ __forceinline__ unsigned short f2b(float f) {
  unsigned int u = __builtin_bit_cast(unsigned int, f);
  u += 0x7fffu + ((u >> 16) & 1u);   // round-to-nearest-even
  return (unsigned short)(u >> 16);
}
__device__ __forceinline__ float b2f(unsigned short h) {
  unsigned int u = ((unsigned int)h) << 16;
  return __builtin_bit_cast(float, u);
}

// ------- prep (grid-stride): converts + bias packing + rowsum zero -------
__global__ __launch_bounds__(256) void prep_kernel(
    const float* __restrict__ x,
    const float* __restrict__ Wq, const float* __restrict__ Wk,
    const float* __restrict__ Wv, const float* __restrict__ Wo,
    const float* __restrict__ bq, const float* __restrict__ bk,
    const float* __restrict__ bv, const float* __restrict__ bo,
    unsigned short* __restrict__ xb, unsigned short* __restrict__ Wqkvb,
    unsigned short* __restrict__ Wob, float* __restrict__ bws,
    float* __restrict__ rows) {
  const unsigned stride = gridDim.x * 256u;
  for (unsigned i = blockIdx.x * 256u + threadIdx.x; i < 3148800u; i += stride) {
    if (i < 2097152u) {
      fl4 f = *(const fl4*)&x[(size_t)i << 2];
      us4 o;
#pragma unroll
      for (int j = 0; j < 4; ++j) o[j] = f2b(f[j]);
      *(us4*)&xb[(size_t)i << 2] = o;
    } else if (i < 3145728u) {
      const unsigned k = i - 2097152u;
      const int w = k >> 18;
      const unsigned idx = k & 262143u;
      const float* s = w == 0 ? Wq : w == 1 ? Wk : w == 2 ? Wv : Wo;
      unsigned short* d = w < 3 ? Wqkvb + (size_t)w * 1024 * 1024 : Wob;
      fl4 f = *(const fl4*)&s[(size_t)idx << 2];
      us4 o;
#pragma unroll
      for (int j = 0; j < 4; ++j) o[j] = f2b(f[j]);
      *(us4*)&d[(size_t)idx << 2] = o;
    } else if (i < 3146752u) {
      const unsigned j = i - 3145728u;
      const int sel = j >> 8;
      const unsigned within = j & 255u;
      const float* p = sel == 0 ? bq : sel == 1 ? bk : sel == 2 ? bv : bo;
      *(fl4*)&bws[(size_t)j << 2] = *(const fl4*)&p[(size_t)within << 2];
    } else {
      const unsigned j = i - 3146752u;
      *(fl4*)&rows[(size_t)j << 2] = fl4{0.f, 0.f, 0.f, 0.f};
    }
  }
}

#define RD_A(dst, basep)                                                   \
  _Pragma("unroll") for (int mi = 0; mi < 4; ++mi)                         \
  _Pragma("unroll") for (int ks = 0; ks < 2; ++ks)                         \
      dst[mi][ks] = *(const short8*)((basep) + offA[mi][ks]);

#define RD_B(dst, basep)                                                   \
  _Pragma("unroll") for (int nj = 0; nj < 2; ++nj)                         \
  _Pragma("unroll") for (int ks = 0; ks < 2; ++ks)                         \
      dst[nj][ks] = *(const short8*)((basep) + offB[nj][ks]);

#define MFMA16(AF, BF, MI0, NJ0)                                           \
  __builtin_amdgcn_s_setprio(1);                                           \
  _Pragma("unroll") for (int ks = 0; ks < 2; ++ks)                         \
  _Pragma("unroll") for (int mi = 0; mi < 4; ++mi)                         \
  _Pragma("unroll") for (int nj = 0; nj < 2; ++nj)                         \
      acc[(MI0) + mi][(NJ0) + nj] = __builtin_amdgcn_mfma_f32_16x16x32_bf16( \
          AF[mi][ks], BF[nj][ks], acc[(MI0) + mi][(NJ0) + nj], 0, 0, 0);   \
  __builtin_amdgcn_s_setprio(0);

// Deep-staged 8-barrier K-loop (T4: +2-tile stage lead, one vmcnt(8)/tile).
#define KLOOP_BODY                                                         \
  stA(0, 0, 0); stB(0, 0, 0); stA(0, 1, 0); stB(0, 1, 0);                  \
  stA(1, 0, 1); stB(1, 0, 1); stA(1, 1, 1); stB(1, 1, 1);                  \
  asm volatile("s_waitcnt vmcnt(8)" ::: "memory");                         \
  __builtin_amdgcn_s_barrier();                                            \
  for (int t = 0; t < nt; ++t) {                                           \
    const int buf = t & 1;                                                 \
    const char* Ab0 = (const char*)&lA[buf][0][0];                         \
    const char* Ab1 = (const char*)&lA[buf][1][0];                         \
    const char* Bb0 = (const char*)&lB[buf][0][0];                         \
    const char* Bb1 = (const char*)&lB[buf][1][0];                         \
    short8 a0[4][2], a1[4][2], b0[2][2], b1[2][2];                         \
    RD_A(a0, Ab0);                                                         \
    RD_B(b0, Bb0);                                                         \
    __builtin_amdgcn_s_barrier();                                          \
    MFMA16(a0, b0, 0, 0);                                                  \
    __builtin_amdgcn_s_barrier();                                          \
    RD_A(a1, Ab1);                                                         \
    stA(buf, 0, t + 2);                                                    \
    stB(buf, 0, t + 2);                                                    \
    __builtin_amdgcn_s_barrier();                                          \
    MFMA16(a1, b0, 4, 0);                                                  \
    __builtin_amdgcn_s_barrier();                                          \
    RD_B(b1, Bb1);                                                         \
    stA(buf, 1, t + 2);                                                    \
    __builtin_amdgcn_s_barrier();                                          \
    MFMA16(a1, b1, 4, 2);                                                  \
    __builtin_amdgcn_s_barrier();                                          \
    stB(buf, 1, t + 2);                                                    \
    asm volatile("s_waitcnt vmcnt(8)" ::: "memory");                       \
    __builtin_amdgcn_s_barrier();                                          \
    MFMA16(a0, b1, 0, 2);                                                  \
    __builtin_amdgcn_s_barrier();                                          \
  }                                                                        \
  asm volatile("s_waitcnt vmcnt(0)" ::: "memory");

// ---------------- gemm8: 256x256 deep-staged pipelined ----------------
// EPI: 3 = bf16 + bias[col]   5 = split-K2 bf16 partial (half -> P0|P1)
//      6 = scores: bf16 exp(v*scale) causal-masked + rowsum atomics
template<int EPI, bool SPLIT2, bool SKIP_UPPER>
__global__ __launch_bounds__(512, 2)
void gemm8(const unsigned short* __restrict__ A, const unsigned short* __restrict__ B,
           void* __restrict__ Cout, const float* __restrict__ bias,
           float* __restrict__ rows, float scale, int K,
           int lda, int ldb, int ldc,
           long long sAz, long long sBz, long long sCz)
{
  const int gx = gridDim.x;
  const int nwg = gx * gridDim.y;
  int flat = blockIdx.y * gx + blockIdx.x;
  { const int q = nwg >> 3, r = nwg & 7, xc = flat & 7, i = flat >> 3;
    flat = (xc < r ? xc * (q + 1) : r * (q + 1) + (xc - r) * q) + i; }
  const int m0 = (flat / gx) << 8;
  const int n0 = (flat % gx) << 8;
  if (SKIP_UPPER && n0 > m0 + 255) return;   // fully-masked score block
  const int zraw = blockIdx.z;
  const int z = SPLIT2 ? (zraw >> 1) : zraw;

  int kBeg = 0, kEnd = K;
  if (SPLIT2) {                        // balanced causal half (PV)
    const int kFull = m0 + 256;
    const int kMid = kFull >> 1;
    kBeg = (zraw & 1) ? kMid : 0;
    kEnd = (zraw & 1) ? kFull : kMid;
  }
  const int nt = (kEnd - kBeg) >> 6;

  __shared__ unsigned short lA[2][2][8192];
  __shared__ unsigned short lB[2][2][8192];

  const int tid = threadIdx.x, lane = tid & 63, wid = tid >> 6;
  const int wm = wid >> 2, wn = wid & 3;
  const int fr = lane & 15, kg = lane >> 4;

  const unsigned short* Ab = A + (size_t)z * sAz;
  const unsigned short* Bb = B + (size_t)z * sBz;

  const int xorv = (fr & 7) << 4;
  int offA[4][2], offB[2][2];
#pragma unroll
  for (int mi = 0; mi < 4; ++mi)
#pragma unroll
    for (int ks = 0; ks < 2; ++ks)
      offA[mi][ks] = ((wm << 6) + (mi << 4) + fr) * 128 + (((ks << 6) + (kg << 4)) ^ xorv);
#pragma unroll
  for (int nj = 0; nj < 2; ++nj)
#pragma unroll
    for (int ks = 0; ks < 2; ++ks)
      offB[nj][ks] = ((wn << 5) + (nj << 4) + fr) * 128 + (((ks << 6) + (kg << 4)) ^ xorv);

  const int srow = tid >> 3;
  const int scol = (((tid & 7) ^ (srow & 7)) << 3);
  const unsigned short* aS = Ab + (size_t)(m0 + srow) * lda + scol + kBeg;
  const unsigned short* bS = Bb + (size_t)(n0 + srow) * ldb + scol + kBeg;

  auto stA = [&](int buf, int h, int tt) {
    int ttc = tt < nt ? tt : nt - 1;
    const unsigned short* s0 = aS + (size_t)(h << 7) * lda + (ttc << 6);
#pragma unroll
    for (int c = 0; c < 2; ++c)
      __builtin_amdgcn_global_load_lds(
          (const __attribute__((address_space(1))) void*)(s0 + (size_t)(c << 6) * lda),
          (__attribute__((address_space(3))) void*)((char*)&lA[buf][h][0] + (c << 13) + (tid << 4)),
          16, 0, 0);
  };
  auto stB = [&](int buf, int h, int tt) {
    int ttc = tt < nt ? tt : nt - 1;
    const unsigned short* s0 = bS + (size_t)(h << 7) * ldb + (ttc << 6);
#pragma unroll
    for (int c = 0; c < 2; ++c)
      __builtin_amdgcn_global_load_lds(
          (const __attribute__((address_space(1))) void*)(s0 + (size_t)(c << 6) * ldb),
          (__attribute__((address_space(3))) void*)((char*)&lB[buf][h][0] + (c << 13) + (tid << 4)),
          16, 0, 0);
  };

  f32x4 acc[8][4];
#pragma unroll
  for (int i = 0; i < 8; ++i)
#pragma unroll
    for (int j = 0; j < 4; ++j) acc[i][j] = f32x4{0.f, 0.f, 0.f, 0.f};

  KLOOP_BODY

  if (EPI == 6) {
    unsigned short* Ch = (unsigned short*)Cout + (size_t)z * sCz;
#pragma unroll
    for (int mig = 0; mig < 8; ++mig) {
      const int row = m0 + (mig >> 2) * 128 + wm * 64 + (mig & 3) * 16 + (kg << 2);
#pragma unroll
      for (int jj = 0; jj < 4; ++jj) {
        const int r = row + jj;
        float rs = 0.f;
#pragma unroll
        for (int njg = 0; njg < 4; ++njg) {
          const int col = n0 + (njg >> 1) * 128 + wn * 32 + (njg & 1) * 16 + fr;
          const float ee = (col <= r) ? __expf(acc[mig][njg][jj] * scale) : 0.f;
          rs += ee;
          Ch[(size_t)r * ldc + col] = f2b(ee);
        }
#pragma unroll
        for (int mk = 1; mk <= 8; mk <<= 1) rs += __shfl_xor(rs, mk, 64);
        if (fr == 0) atomicAdd(&rows[z * 2048 + r], rs);
      }
    }
    return;
  }
#pragma unroll
  for (int mig = 0; mig < 8; ++mig)
#pragma unroll
    for (int njg = 0; njg < 4; ++njg) {
      const int row = m0 + (mig >> 2) * 128 + wm * 64 + (mig & 3) * 16 + (kg << 2);
      const int col = n0 + (njg >> 1) * 128 + wn * 32 + (njg & 1) * 16 + fr;
      f32x4 v = acc[mig][njg];
      if (EPI == 3) {
        unsigned short* Ch = (unsigned short*)Cout;
        const float bb = bias[col];
#pragma unroll
        for (int jj = 0; jj < 4; ++jj)
          Ch[(size_t)(row + jj) * ldc + col] = f2b(v[jj] + bb);
      } else {   // EPI == 5: split-K2 partial; half selects P0|P1
        unsigned short* Ch = (unsigned short*)Cout +
            (size_t)(zraw & 1) * 8388608 + (size_t)z * sCz;
#pragma unroll
        for (int jj = 0; jj < 4; ++jj)
          Ch[(size_t)(row + jj) * ldc + col] = f2b(v[jj]);
      }
    }
}

// ---------------- gemm2ph: 256x128 2-phase, 4-barrier ----------------
// EPI: 2 = f32 + bias[col] (out-proj)   4 = bf16 + bias[row] (Vt-proj)
template<int EPI>
__global__ __launch_bounds__(512, 2)
void gemm2ph(const unsigned short* __restrict__ A, const unsigned short* __restrict__ B,
             void* __restrict__ Cout, const float* __restrict__ bias,
             int K, int lda, int ldb, int ldc)
{
  const int gx = gridDim.x;
  const int nwg = gx * gridDim.y;
  int flat = blockIdx.y * gx + blockIdx.x;
  { const int q = nwg >> 3, r = nwg & 7, xc = flat & 7, i = flat >> 3;
    flat = (xc < r ? xc * (q + 1) : r * (q + 1) + (xc - r) * q) + i; }
  const int m0 = (flat / gx) << 8;
  const int n0 = (flat % gx) << 7;
  const int nt = K >> 6;

  __shared__ unsigned short lA[2][2][8192];   // 64 KB
  __shared__ unsigned short lB[2][8192];      // 32 KB

  const int tid = threadIdx.x, lane = tid & 63, wid = tid >> 6;
  const int wm = wid >> 2, wn = wid & 3;
  const int fr = lane & 15, kg = lane >> 4;

  const int xorv = (fr & 7) << 4;
  int offA[4][2], offB[2][2];
#pragma unroll
  for (int mi = 0; mi < 4; ++mi)
#pragma unroll
    for (int ks = 0; ks < 2; ++ks)
      offA[mi][ks] = ((wm << 6) + (mi << 4) + fr) * 128 + (((ks << 6) + (kg << 4)) ^ xorv);
#pragma unroll
  for (int nj = 0; nj < 2; ++nj)
#pragma unroll
    for (int ks = 0; ks < 2; ++ks)
      offB[nj][ks] = ((wn << 5) + (nj << 4) + fr) * 128 + (((ks << 6) + (kg << 4)) ^ xorv);

  const int srow = tid >> 3;
  const int scol = (((tid & 7) ^ (srow & 7)) << 3);
  const unsigned short* aS = A + (size_t)(m0 + srow) * lda + scol;
  const unsigned short* bS = B + (size_t)(n0 + srow) * ldb + scol;

  auto stA = [&](int buf, int h, int tt) {
    int ttc = tt < nt ? tt : nt - 1;
    const unsigned short* s0 = aS + (size_t)(h << 7) * lda + (ttc << 6);
#pragma unroll
    for (int c = 0; c < 2; ++c)
      __builtin_amdgcn_global_load_lds(
          (const __attribute__((address_space(1))) void*)(s0 + (size_t)(c << 6) * lda),
          (__attribute__((address_space(3))) void*)((char*)&lA[buf][h][0] + (c << 13) + (tid << 4)),
          16, 0, 0);
  };
  auto stB = [&](int buf, int tt) {
    int ttc = tt < nt ? tt : nt - 1;
    const unsigned short* s0 = bS + (ttc << 6);
#pragma unroll
    for (int c = 0; c < 2; ++c)
      __builtin_amdgcn_global_load_lds(
          (const __attribute__((address_space(1))) void*)(s0 + (size_t)(c << 6) * ldb),
          (__attribute__((address_space(3))) void*)((char*)&lB[buf][0] + (c << 13) + (tid << 4)),
          16, 0, 0);
  };

  f32x4 acc[8][2];
#pragma unroll
  for (int i = 0; i < 8; ++i)
#pragma unroll
    for (int j = 0; j < 2; ++j) acc[i][j] = f32x4{0.f, 0.f, 0.f, 0.f};

  stB(0, 0); stA(0, 0, 0); stA(0, 1, 0);
  asm volatile("s_waitcnt vmcnt(2)" ::: "memory");
  __builtin_amdgcn_s_barrier();

  for (int t = 0; t < nt; ++t) {
    const int buf = t & 1, nbuf = buf ^ 1;
    const char* Ab0 = (const char*)&lA[buf][0][0];
    const char* Ab1 = (const char*)&lA[buf][1][0];
    const char* Bbp = (const char*)&lB[buf][0];

    short8 a0[4][2], a1[4][2], b0[2][2];

    RD_A(a0, Ab0);
    RD_B(b0, Bbp);
    stB(nbuf, t + 1); stA(nbuf, 0, t + 1);
    asm volatile("s_waitcnt vmcnt(4)" ::: "memory");
    __builtin_amdgcn_s_barrier();
    MFMA16(a0, b0, 0, 0);
    __builtin_amdgcn_s_barrier();

    RD_A(a1, Ab1);
    stA(nbuf, 1, t + 1);
    asm volatile("s_waitcnt vmcnt(2)" ::: "memory");
    __builtin_amdgcn_s_barrier();
    MFMA16(a1, b0, 4, 0);
    __builtin_amdgcn_s_barrier();
  }
  asm volatile("s_waitcnt vmcnt(0)" ::: "memory");

#pragma unroll
  for (int mig = 0; mig < 8; ++mig)
#pragma unroll
    for (int njg = 0; njg < 2; ++njg) {
      const int row = m0 + (mig >> 2) * 128 + wm * 64 + (mig & 3) * 16 + (kg << 2);
      const int col = n0 + wn * 32 + njg * 16 + fr;
      f32x4 v = acc[mig][njg];
      if (EPI == 2) {
        float* Cf = (float*)Cout;
        const float bb = bias[col];
#pragma unroll
        for (int jj = 0; jj < 4; ++jj)
          Cf[(size_t)(row + jj) * ldc + col] = v[jj] + bb;
      } else {   // EPI == 4: bias by row (Vt-proj)
        unsigned short* Ch = (unsigned short*)Cout;
#pragma unroll
        for (int jj = 0; jj < 4; ++jj)
          Ch[(size_t)(row + jj) * ldc + col] = f2b(v[jj] + bias[row + jj]);
      }
    }
}

// ---- split-K2 reduce + normalize (grid-stride): attn = (P0+P1)/rowsum ----
__global__ __launch_bounds__(256)
void reduce_pv2(const unsigned short* __restrict__ p0,
                const unsigned short* __restrict__ p1,
                const float* __restrict__ rows,
                unsigned short* __restrict__ out) {
  const unsigned stride = gridDim.x * 256u;
  for (unsigned g = blockIdx.x * 256u + threadIdx.x; g < 1048576u; g += stride) {
    const size_t i = (size_t)g << 3;
    const float inv = 1.f / rows[i >> 10];
    us8 a = *(const us8*)&p0[i];
    us8 b = *(const us8*)&p1[i];
    us8 o;
#pragma unroll
    for (int j = 0; j < 8; ++j)
      o[j] = f2b((b2f(a[j]) + b2f(b[j])) * inv);
    *(us8*)&out[i] = o;
  }
}

// ---------------- host-side launch ----------------
extern "C" void kernel_launch(void* const* d_in, const int* in_sizes, int n_in,
                              void* d_out, int out_size, void* d_ws, size_t ws_size,
                              hipStream_t stream) {
  (void)in_sizes; (void)n_in; (void)out_size; (void)ws_size;
  const float* x  = (const float*)d_in[0];
  const float* Wq = (const float*)d_in[1];
  const float* bq = (const float*)d_in[2];
  const float* Wk = (const float*)d_in[3];
  const float* bk = (const float*)d_in[4];
  const float* Wv = (const float*)d_in[5];
  const float* bv = (const float*)d_in[6];
  const float* Wo = (const float*)d_in[7];
  const float* bo = (const float*)d_in[8];

  const int B = 4, T = 2048, C = 1024;
  const int M = B * T;                                   // 8192

  unsigned short* xb    = (unsigned short*)d_ws;         // M*C
  unsigned short* Wqkvb = xb    + (size_t)M * C;         // [Wq|Wk|Wv]
  unsigned short* Wob   = Wqkvb + (size_t)3 * C * C;
  unsigned short* QK    = Wob   + (size_t)C * C;         // M*2C [Q|K]; later P0|P1
  unsigned short* Vt    = QK    + (size_t)M * 2 * C;     // [1024][8192]
  unsigned short* S     = Vt    + (size_t)M * C;         // B*T*T e-values
  float*          bws   = (float*)(S + (size_t)B * T * T);
  float*          rowsum= bws + 4096;                    // 8192 f32
  unsigned short* P0    = QK;
  unsigned short* P1    = QK + (size_t)M * C;
  unsigned short* attn  = P0;

  // 1. prep (grid-stride, 2048 blocks)
  prep_kernel<<<2048, 256, 0, stream>>>(x, Wq, Wk, Wv, Wo, bq, bk, bv, bo,
                                        xb, Wqkvb, Wob, bws, rowsum);

  // 2. QK projection (256 blocks)
  gemm8<3, false, false><<<dim3(2 * C / 256, M / 256, 1), 512, 0, stream>>>(
      xb, Wqkvb, QK, bws, nullptr, 1.f, C, C, C, 2 * C, 0LL, 0LL, 0LL);

  // 3. Vt = Wv @ x^T + bv[row] (256 blocks, BN=128)
  gemm2ph<4><<<dim3(M / 128, C / 256, 1), 512, 0, stream>>>(
      Wqkvb + (size_t)2 * C * C, xb, Vt, bws + 2 * C, C, C, C, M);

  // 4. scores: S = exp(Q K^T / 32) causal-masked + rowsum atomics
  gemm8<6, false, true><<<dim3(T / 256, T / 256, B), 512, 0, stream>>>(
      QK, QK + C, S, nullptr, rowsum, 0.03125f, C, 2 * C, 2 * C, T,
      (long long)T * 2 * C, (long long)T * 2 * C, (long long)T * T);

  // 5. PV split-K2: partials P0|P1 (z = batch*2 + half), 256 blocks
  gemm8<5, true, false><<<dim3(C / 256, T / 256, 2 * B), 512, 0, stream>>>(
      S, Vt, P0, nullptr, nullptr, 1.f, T, T, M, C,
      (long long)T * T, 2048LL, (long long)T * C);

  // 6. reduce + normalize (grid-stride, 2048 blocks; attn -> P0 in place)
  reduce_pv2<<<2048, 256, 0, stream>>>(P0, P1, rowsum, attn);

  // 7. out = attn Wo^T + bo (f32, 256 blocks BN=128)
  gemm2ph<2><<<dim3(C / 128, M / 256, 1), 512, 0, stream>>>(
      attn, Wob, d_out, bws + 3 * C, C, C, C, C);
}

// Round 22
// 181.889 us; speedup vs baseline: 1.0485x; 1.0001x over previous
//
#include <hip/hip_runtime.h>

// Masked self-attention, B=4 T=2048 C=1024 (single head, head dim = C).
// FINAL BANKED CONFIGURATION (measured 181.4-181.9 µs across 4 runs).
//  gemm8  : 256x256 / BK=64 / 8-wave deep-staged pipelined (+2-tile stage
//           lead into current buf, one vmcnt(8)/K-tile, 2 barriers/phase).
//           EPI 3 = bf16+bias[col] (QK), 5 = split-K2 partial (PV),
//           6 = scores exp+rowsum (tri early-exit).
//  gemm2ph: 256x128 2-phase (Vt-proj bf16+bias[row]; out-proj f32+bias[col]).
// LDS swizzle: 16B-slot ^= (row&7), both-sides. T1 XCD-bijective swizzle.
// Softmax fused in scores epilogue; reduce_pv2 divides by rowsum.
// prep/reduce: 2048-block grid-stride.
// Pipeline: prep | QK | Vt | scores | PV splitK2 | reduce2 | out.

typedef __attribute__((ext_vector_type(8))) short short8;
typedef __attribute__((ext_vector_type(4))) float f32x4;
typedef __attribute__((ext_vector_type(4))) unsigned short us4;
typedef __attribute__((ext_vector_type(8))) unsigned short us8;
typedef __attribute__((ext_vector_type(4))) float fl4;

__device__ __forceinline__ unsigned short f2b(float f) {
  unsigned int u = __builtin_bit_cast(unsigned int, f);
  u += 0x7fffu + ((u >> 16) & 1u);   // round-to-nearest-even
  return (unsigned short)(u >> 16);
}
__device__ __forceinline__ float b2f(unsigned short h) {
  unsigned int u = ((unsigned int)h) << 16;
  return __builtin_bit_cast(float, u);
}

// ------- prep (grid-stride): converts + bias packing + rowsum zero -------
__global__ __launch_bounds__(256) void prep_kernel(
    const float* __restrict__ x,
    const float* __restrict__ Wq, const float* __restrict__ Wk,
    const float* __restrict__ Wv, const float* __restrict__ Wo,
    const float* __restrict__ bq, const float* __restrict__ bk,
    const float* __restrict__ bv, const float* __restrict__ bo,
    unsigned short* __restrict__ xb, unsigned short* __restrict__ Wqkvb,
    unsigned short* __restrict__ Wob, float* __restrict__ bws,
    float* __restrict__ rows) {
  const unsigned stride = gridDim.x * 256u;
  for (unsigned i = blockIdx.x * 256u + threadIdx.x; i < 3148800u; i += stride) {
    if (i < 2097152u) {
      fl4 f = *(const fl4*)&x[(size_t)i << 2];
      us4 o;
#pragma unroll
      for (int j = 0; j < 4; ++j) o[j] = f2b(f[j]);
      *(us4*)&xb[(size_t)i << 2] = o;
    } else if (i < 3145728u) {
      const unsigned k = i - 2097152u;
      const int w = k >> 18;
      const unsigned idx = k & 262143u;
      const float* s = w == 0 ? Wq : w == 1 ? Wk : w == 2 ? Wv : Wo;
      unsigned short* d = w < 3 ? Wqkvb + (size_t)w * 1024 * 1024 : Wob;
      fl4 f = *(const fl4*)&s[(size_t)idx << 2];
      us4 o;
#pragma unroll
      for (int j = 0; j < 4; ++j) o[j] = f2b(f[j]);
      *(us4*)&d[(size_t)idx << 2] = o;
    } else if (i < 3146752u) {
      const unsigned j = i - 3145728u;
      const int sel = j >> 8;
      const unsigned within = j & 255u;
      const float* p = sel == 0 ? bq : sel == 1 ? bk : sel == 2 ? bv : bo;
      *(fl4*)&bws[(size_t)j << 2] = *(const fl4*)&p[(size_t)within << 2];
    } else {
      const unsigned j = i - 3146752u;
      *(fl4*)&rows[(size_t)j << 2] = fl4{0.f, 0.f, 0.f, 0.f};
    }
  }
}

#define RD_A(dst, basep)                                                   \
  _Pragma("unroll") for (int mi = 0; mi < 4; ++mi)                         \
  _Pragma("unroll") for (int ks = 0; ks < 2; ++ks)                         \
      dst[mi][ks] = *(const short8*)((basep) + offA[mi][ks]);

#define RD_B(dst, basep)                                                   \
  _Pragma("unroll") for (int nj = 0; nj < 2; ++nj)                         \
  _Pragma("unroll") for (int ks = 0; ks < 2; ++ks)                         \
      dst[nj][ks] = *(const short8*)((basep) + offB[nj][ks]);

#define MFMA16(AF, BF, MI0, NJ0)                                           \
  __builtin_amdgcn_s_setprio(1);                                           \
  _Pragma("unroll") for (int ks = 0; ks < 2; ++ks)                         \
  _Pragma("unroll") for (int mi = 0; mi < 4; ++mi)                         \
  _Pragma("unroll") for (int nj = 0; nj < 2; ++nj)                         \
      acc[(MI0) + mi][(NJ0) + nj] = __builtin_amdgcn_mfma_f32_16x16x32_bf16( \
          AF[mi][ks], BF[nj][ks], acc[(MI0) + mi][(NJ0) + nj], 0, 0, 0);   \
  __builtin_amdgcn_s_setprio(0);

// Deep-staged 8-barrier K-loop (T4: +2-tile stage lead, one vmcnt(8)/tile).
#define KLOOP_BODY                                                         \
  stA(0, 0, 0); stB(0, 0, 0); stA(0, 1, 0); stB(0, 1, 0);                  \
  stA(1, 0, 1); stB(1, 0, 1); stA(1, 1, 1); stB(1, 1, 1);                  \
  asm volatile("s_waitcnt vmcnt(8)" ::: "memory");                         \
  __builtin_amdgcn_s_barrier();                                            \
  for (int t = 0; t < nt; ++t) {                                           \
    const int buf = t & 1;                                                 \
    const char* Ab0 = (const char*)&lA[buf][0][0];                         \
    const char* Ab1 = (const char*)&lA[buf][1][0];                         \
    const char* Bb0 = (const char*)&lB[buf][0][0];                         \
    const char* Bb1 = (const char*)&lB[buf][1][0];                         \
    short8 a0[4][2], a1[4][2], b0[2][2], b1[2][2];                         \
    RD_A(a0, Ab0);                                                         \
    RD_B(b0, Bb0);                                                         \
    __builtin_amdgcn_s_barrier();                                          \
    MFMA16(a0, b0, 0, 0);                                                  \
    __builtin_amdgcn_s_barrier();                                          \
    RD_A(a1, Ab1);                                                         \
    stA(buf, 0, t + 2);                                                    \
    stB(buf, 0, t + 2);                                                    \
    __builtin_amdgcn_s_barrier();                                          \
    MFMA16(a1, b0, 4, 0);                                                  \
    __builtin_amdgcn_s_barrier();                                          \
    RD_B(b1, Bb1);                                                         \
    stA(buf, 1, t + 2);                                                    \
    __builtin_amdgcn_s_barrier();                                          \
    MFMA16(a1, b1, 4, 2);                                                  \
    __builtin_amdgcn_s_barrier();                                          \
    stB(buf, 1, t + 2);                                                    \
    asm volatile("s_waitcnt vmcnt(8)" ::: "memory");                       \
    __builtin_amdgcn_s_barrier();                                          \
    MFMA16(a0, b1, 0, 2);                                                  \
    __builtin_amdgcn_s_barrier();                                          \
  }                                                                        \
  asm volatile("s_waitcnt vmcnt(0)" ::: "memory");

// ---------------- gemm8: 256x256 deep-staged pipelined ----------------
// EPI: 3 = bf16 + bias[col]   5 = split-K2 bf16 partial (half -> P0|P1)
//      6 = scores: bf16 exp(v*scale) causal-masked + rowsum atomics
template<int EPI, bool SPLIT2, bool SKIP_UPPER>
__global__ __launch_bounds__(512, 2)
void gemm8(const unsigned short* __restrict__ A, const unsigned short* __restrict__ B,
           void* __restrict__ Cout, const float* __restrict__ bias,
           float* __restrict__ rows, float scale, int K,
           int lda, int ldb, int ldc,
           long long sAz, long long sBz, long long sCz)
{
  const int gx = gridDim.x;
  const int nwg = gx * gridDim.y;
  int flat = blockIdx.y * gx + blockIdx.x;
  { const int q = nwg >> 3, r = nwg & 7, xc = flat & 7, i = flat >> 3;
    flat = (xc < r ? xc * (q + 1) : r * (q + 1) + (xc - r) * q) + i; }
  const int m0 = (flat / gx) << 8;
  const int n0 = (flat % gx) << 8;
  if (SKIP_UPPER && n0 > m0 + 255) return;   // fully-masked score block
  const int zraw = blockIdx.z;
  const int z = SPLIT2 ? (zraw >> 1) : zraw;

  int kBeg = 0, kEnd = K;
  if (SPLIT2) {                        // balanced causal half (PV)
    const int kFull = m0 + 256;
    const int kMid = kFull >> 1;
    kBeg = (zraw & 1) ? kMid : 0;
    kEnd = (zraw & 1) ? kFull : kMid;
  }
  const int nt = (kEnd - kBeg) >> 6;

  __shared__ unsigned short lA[2][2][8192];
  __shared__ unsigned short lB[2][2][8192];

  const int tid = threadIdx.x, lane = tid & 63, wid = tid >> 6;
  const int wm = wid >> 2, wn = wid & 3;
  const int fr = lane & 15, kg = lane >> 4;

  const unsigned short* Ab = A + (size_t)z * sAz;
  const unsigned short* Bb = B + (size_t)z * sBz;

  const int xorv = (fr & 7) << 4;
  int offA[4][2], offB[2][2];
#pragma unroll
  for (int mi = 0; mi < 4; ++mi)
#pragma unroll
    for (int ks = 0; ks < 2; ++ks)
      offA[mi][ks] = ((wm << 6) + (mi << 4) + fr) * 128 + (((ks << 6) + (kg << 4)) ^ xorv);
#pragma unroll
  for (int nj = 0; nj < 2; ++nj)
#pragma unroll
    for (int ks = 0; ks < 2; ++ks)
      offB[nj][ks] = ((wn << 5) + (nj << 4) + fr) * 128 + (((ks << 6) + (kg << 4)) ^ xorv);

  const int srow = tid >> 3;
  const int scol = (((tid & 7) ^ (srow & 7)) << 3);
  const unsigned short* aS = Ab + (size_t)(m0 + srow) * lda + scol + kBeg;
  const unsigned short* bS = Bb + (size_t)(n0 + srow) * ldb + scol + kBeg;

  auto stA = [&](int buf, int h, int tt) {
    int ttc = tt < nt ? tt : nt - 1;
    const unsigned short* s0 = aS + (size_t)(h << 7) * lda + (ttc << 6);
#pragma unroll
    for (int c = 0; c < 2; ++c)
      __builtin_amdgcn_global_load_lds(
          (const __attribute__((address_space(1))) void*)(s0 + (size_t)(c << 6) * lda),
          (__attribute__((address_space(3))) void*)((char*)&lA[buf][h][0] + (c << 13) + (tid << 4)),
          16, 0, 0);
  };
  auto stB = [&](int buf, int h, int tt) {
    int ttc = tt < nt ? tt : nt - 1;
    const unsigned short* s0 = bS + (size_t)(h << 7) * ldb + (ttc << 6);
#pragma unroll
    for (int c = 0; c < 2; ++c)
      __builtin_amdgcn_global_load_lds(
          (const __attribute__((address_space(1))) void*)(s0 + (size_t)(c << 6) * ldb),
          (__attribute__((address_space(3))) void*)((char*)&lB[buf][h][0] + (c << 13) + (tid << 4)),
          16, 0, 0);
  };

  f32x4 acc[8][4];
#pragma unroll
  for (int i = 0; i < 8; ++i)
#pragma unroll
    for (int j = 0; j < 4; ++j) acc[i][j] = f32x4{0.f, 0.f, 0.f, 0.f};

  KLOOP_BODY

  if (EPI == 6) {
    unsigned short* Ch = (unsigned short*)Cout + (size_t)z * sCz;
#pragma unroll
    for (int mig = 0; mig < 8; ++mig) {
      const int row = m0 + (mig >> 2) * 128 + wm * 64 + (mig & 3) * 16 + (kg << 2);
#pragma unroll
      for (int jj = 0; jj < 4; ++jj) {
        const int r = row + jj;
        float rs = 0.f;
#pragma unroll
        for (int njg = 0; njg < 4; ++njg) {
          const int col = n0 + (njg >> 1) * 128 + wn * 32 + (njg & 1) * 16 + fr;
          const float ee = (col <= r) ? __expf(acc[mig][njg][jj] * scale) : 0.f;
          rs += ee;
          Ch[(size_t)r * ldc + col] = f2b(ee);
        }
#pragma unroll
        for (int mk = 1; mk <= 8; mk <<= 1) rs += __shfl_xor(rs, mk, 64);
        if (fr == 0) atomicAdd(&rows[z * 2048 + r], rs);
      }
    }
    return;
  }
#pragma unroll
  for (int mig = 0; mig < 8; ++mig)
#pragma unroll
    for (int njg = 0; njg < 4; ++njg) {
      const int row = m0 + (mig >> 2) * 128 + wm * 64 + (mig & 3) * 16 + (kg << 2);
      const int col = n0 + (njg >> 1) * 128 + wn * 32 + (njg & 1) * 16 + fr;
      f32x4 v = acc[mig][njg];
      if (EPI == 3) {
        unsigned short* Ch = (unsigned short*)Cout;
        const float bb = bias[col];
#pragma unroll
        for (int jj = 0; jj < 4; ++jj)
          Ch[(size_t)(row + jj) * ldc + col] = f2b(v[jj] + bb);
      } else {   // EPI == 5: split-K2 partial; half selects P0|P1
        unsigned short* Ch = (unsigned short*)Cout +
            (size_t)(zraw & 1) * 8388608 + (size_t)z * sCz;
#pragma unroll
        for (int jj = 0; jj < 4; ++jj)
          Ch[(size_t)(row + jj) * ldc + col] = f2b(v[jj]);
      }
    }
}

// ---------------- gemm2ph: 256x128 2-phase, 4-barrier ----------------
// EPI: 2 = f32 + bias[col] (out-proj)   4 = bf16 + bias[row] (Vt-proj)
template<int EPI>
__global__ __launch_bounds__(512, 2)
void gemm2ph(const unsigned short* __restrict__ A, const unsigned short* __restrict__ B,
             void* __restrict__ Cout, const float* __restrict__ bias,
             int K, int lda, int ldb, int ldc)
{
  const int gx = gridDim.x;
  const int nwg = gx * gridDim.y;
  int flat = blockIdx.y * gx + blockIdx.x;
  { const int q = nwg >> 3, r = nwg & 7, xc = flat & 7, i = flat >> 3;
    flat = (xc < r ? xc * (q + 1) : r * (q + 1) + (xc - r) * q) + i; }
  const int m0 = (flat / gx) << 8;
  const int n0 = (flat % gx) << 7;
  const int nt = K >> 6;

  __shared__ unsigned short lA[2][2][8192];   // 64 KB
  __shared__ unsigned short lB[2][8192];      // 32 KB

  const int tid = threadIdx.x, lane = tid & 63, wid = tid >> 6;
  const int wm = wid >> 2, wn = wid & 3;
  const int fr = lane & 15, kg = lane >> 4;

  const int xorv = (fr & 7) << 4;
  int offA[4][2], offB[2][2];
#pragma unroll
  for (int mi = 0; mi < 4; ++mi)
#pragma unroll
    for (int ks = 0; ks < 2; ++ks)
      offA[mi][ks] = ((wm << 6) + (mi << 4) + fr) * 128 + (((ks << 6) + (kg << 4)) ^ xorv);
#pragma unroll
  for (int nj = 0; nj < 2; ++nj)
#pragma unroll
    for (int ks = 0; ks < 2; ++ks)
      offB[nj][ks] = ((wn << 5) + (nj << 4) + fr) * 128 + (((ks << 6) + (kg << 4)) ^ xorv);

  const int srow = tid >> 3;
  const int scol = (((tid & 7) ^ (srow & 7)) << 3);
  const unsigned short* aS = A + (size_t)(m0 + srow) * lda + scol;
  const unsigned short* bS = B + (size_t)(n0 + srow) * ldb + scol;

  auto stA = [&](int buf, int h, int tt) {
    int ttc = tt < nt ? tt : nt - 1;
    const unsigned short* s0 = aS + (size_t)(h << 7) * lda + (ttc << 6);
#pragma unroll
    for (int c = 0; c < 2; ++c)
      __builtin_amdgcn_global_load_lds(
          (const __attribute__((address_space(1))) void*)(s0 + (size_t)(c << 6) * lda),
          (__attribute__((address_space(3))) void*)((char*)&lA[buf][h][0] + (c << 13) + (tid << 4)),
          16, 0, 0);
  };
  auto stB = [&](int buf, int tt) {
    int ttc = tt < nt ? tt : nt - 1;
    const unsigned short* s0 = bS + (ttc << 6);
#pragma unroll
    for (int c = 0; c < 2; ++c)
      __builtin_amdgcn_global_load_lds(
          (const __attribute__((address_space(1))) void*)(s0 + (size_t)(c << 6) * ldb),
          (__attribute__((address_space(3))) void*)((char*)&lB[buf][0] + (c << 13) + (tid << 4)),
          16, 0, 0);
  };

  f32x4 acc[8][2];
#pragma unroll
  for (int i = 0; i < 8; ++i)
#pragma unroll
    for (int j = 0; j < 2; ++j) acc[i][j] = f32x4{0.f, 0.f, 0.f, 0.f};

  stB(0, 0); stA(0, 0, 0); stA(0, 1, 0);
  asm volatile("s_waitcnt vmcnt(2)" ::: "memory");
  __builtin_amdgcn_s_barrier();

  for (int t = 0; t < nt; ++t) {
    const int buf = t & 1, nbuf = buf ^ 1;
    const char* Ab0 = (const char*)&lA[buf][0][0];
    const char* Ab1 = (const char*)&lA[buf][1][0];
    const char* Bbp = (const char*)&lB[buf][0];

    short8 a0[4][2], a1[4][2], b0[2][2];

    RD_A(a0, Ab0);
    RD_B(b0, Bbp);
    stB(nbuf, t + 1); stA(nbuf, 0, t + 1);
    asm volatile("s_waitcnt vmcnt(4)" ::: "memory");
    __builtin_amdgcn_s_barrier();
    MFMA16(a0, b0, 0, 0);
    __builtin_amdgcn_s_barrier();

    RD_A(a1, Ab1);
    stA(nbuf, 1, t + 1);
    asm volatile("s_waitcnt vmcnt(2)" ::: "memory");
    __builtin_amdgcn_s_barrier();
    MFMA16(a1, b0, 4, 0);
    __builtin_amdgcn_s_barrier();
  }
  asm volatile("s_waitcnt vmcnt(0)" ::: "memory");

#pragma unroll
  for (int mig = 0; mig < 8; ++mig)
#pragma unroll
    for (int njg = 0; njg < 2; ++njg) {
      const int row = m0 + (mig >> 2) * 128 + wm * 64 + (mig & 3) * 16 + (kg << 2);
      const int col = n0 + wn * 32 + njg * 16 + fr;
      f32x4 v = acc[mig][njg];
      if (EPI == 2) {
        float* Cf = (float*)Cout;
        const float bb = bias[col];
#pragma unroll
        for (int jj = 0; jj < 4; ++jj)
          Cf[(size_t)(row + jj) * ldc + col] = v[jj] + bb;
      } else {   // EPI == 4: bias by row (Vt-proj)
        unsigned short* Ch = (unsigned short*)Cout;
#pragma unroll
        for (int jj = 0; jj < 4; ++jj)
          Ch[(size_t)(row + jj) * ldc + col] = f2b(v[jj] + bias[row + jj]);
      }
    }
}

// ---- split-K2 reduce + normalize (grid-stride): attn = (P0+P1)/rowsum ----
__global__ __launch_bounds__(256)
void reduce_pv2(const unsigned short* __restrict__ p0,
                const unsigned short* __restrict__ p1,
                const float* __restrict__ rows,
                unsigned short* __restrict__ out) {
  const unsigned stride = gridDim.x * 256u;
  for (unsigned g = blockIdx.x * 256u + threadIdx.x; g < 1048576u; g += stride) {
    const size_t i = (size_t)g << 3;
    const float inv = 1.f / rows[i >> 10];
    us8 a = *(const us8*)&p0[i];
    us8 b = *(const us8*)&p1[i];
    us8 o;
#pragma unroll
    for (int j = 0; j < 8; ++j)
      o[j] = f2b((b2f(a[j]) + b2f(b[j])) * inv);
    *(us8*)&out[i] = o;
  }
}

// ---------------- host-side launch ----------------
extern "C" void kernel_launch(void* const* d_in, const int* in_sizes, int n_in,
                              void* d_out, int out_size, void* d_ws, size_t ws_size,
                              hipStream_t stream) {
  (void)in_sizes; (void)n_in; (void)out_size; (void)ws_size;
  const float* x  = (const float*)d_in[0];
  const float* Wq = (const float*)d_in[1];
  const float* bq = (const float*)d_in[2];
  const float* Wk = (const float*)d_in[3];
  const float* bk = (const float*)d_in[4];
  const float* Wv = (const float*)d_in[5];
  const float* bv = (const float*)d_in[6];
  const float* Wo = (const float*)d_in[7];
  const float* bo = (const float*)d_in[8];

  const int B = 4, T = 2048, C = 1024;
  const int M = B * T;                                   // 8192

  unsigned short* xb    = (unsigned short*)d_ws;         // M*C
  unsigned short* Wqkvb = xb    + (size_t)M * C;         // [Wq|Wk|Wv]
  unsigned short* Wob   = Wqkvb + (size_t)3 * C * C;
  unsigned short* QK    = Wob   + (size_t)C * C;         // M*2C [Q|K]; later P0|P1
  unsigned short* Vt    = QK    + (size_t)M * 2 * C;     // [1024][8192]
  unsigned short* S     = Vt    + (size_t)M * C;         // B*T*T e-values
  float*          bws   = (float*)(S + (size_t)B * T * T);
  float*          rowsum= bws + 4096;                    // 8192 f32
  unsigned short* P0    = QK;
  unsigned short* P1    = QK + (size_t)M * C;
  unsigned short* attn  = P0;

  // 1. prep (grid-stride, 2048 blocks)
  prep_kernel<<<2048, 256, 0, stream>>>(x, Wq, Wk, Wv, Wo, bq, bk, bv, bo,
                                        xb, Wqkvb, Wob, bws, rowsum);

  // 2. QK projection (256 blocks)
  gemm8<3, false, false><<<dim3(2 * C / 256, M / 256, 1), 512, 0, stream>>>(
      xb, Wqkvb, QK, bws, nullptr, 1.f, C, C, C, 2 * C, 0LL, 0LL, 0LL);

  // 3. Vt = Wv @ x^T + bv[row] (256 blocks, BN=128)
  gemm2ph<4><<<dim3(M / 128, C / 256, 1), 512, 0, stream>>>(
      Wqkvb + (size_t)2 * C * C, xb, Vt, bws + 2 * C, C, C, C, M);

  // 4. scores: S = exp(Q K^T / 32) causal-masked + rowsum atomics
  gemm8<6, false, true><<<dim3(T / 256, T / 256, B), 512, 0, stream>>>(
      QK, QK + C, S, nullptr, rowsum, 0.03125f, C, 2 * C, 2 * C, T,
      (long long)T * 2 * C, (long long)T * 2 * C, (long long)T * T);

  // 5. PV split-K2: partials P0|P1 (z = batch*2 + half), 256 blocks
  gemm8<5, true, false><<<dim3(C / 256, T / 256, 2 * B), 512, 0, stream>>>(
      S, Vt, P0, nullptr, nullptr, 1.f, T, T, M, C,
      (long long)T * T, 2048LL, (long long)T * C);

  // 6. reduce + normalize (grid-stride, 2048 blocks; attn -> P0 in place)
  reduce_pv2<<<2048, 256, 0, stream>>>(P0, P1, rowsum, attn);

  // 7. out = attn Wo^T + bo (f32, 256 blocks BN=128)
  gemm2ph<2><<<dim3(C / 128, M / 256, 1), 512, 0, stream>>>(
      attn, Wob, d_out, bws + 3 * C, C, C, C, C);
}

// Round 23
// 181.233 us; speedup vs baseline: 1.0522x; 1.0036x over previous
//
#include <hip/hip_runtime.h>

// Masked self-attention, B=4 T=2048 C=1024 (single head, head dim = C).
// FINAL BANKED CONFIGURATION (measured 181.4-181.9 µs across 5 runs).
//  gemm8  : 256x256 / BK=64 / 8-wave deep-staged pipelined (+2-tile stage
//           lead into current buf, one vmcnt(8)/K-tile, 2 barriers/phase).
//           EPI 3 = bf16+bias[col] (QK), 5 = split-K2 partial (PV),
//           6 = scores exp+rowsum (tri early-exit).
//  gemm2ph: 256x128 2-phase (Vt-proj bf16+bias[row]; out-proj f32+bias[col]).
// LDS swizzle: 16B-slot ^= (row&7), both-sides. T1 XCD-bijective swizzle.
// Softmax fused in scores epilogue; reduce_pv2 divides by rowsum.
// prep/reduce: 2048-block grid-stride.
// Pipeline: prep | QK | Vt | scores | PV splitK2 | reduce2 | out.

typedef __attribute__((ext_vector_type(8))) short short8;
typedef __attribute__((ext_vector_type(4))) float f32x4;
typedef __attribute__((ext_vector_type(4))) unsigned short us4;
typedef __attribute__((ext_vector_type(8))) unsigned short us8;
typedef __attribute__((ext_vector_type(4))) float fl4;

__device__ __forceinline__ unsigned short f2b(float f) {
  unsigned int u = __builtin_bit_cast(unsigned int, f);
  u += 0x7fffu + ((u >> 16) & 1u);   // round-to-nearest-even
  return (unsigned short)(u >> 16);
}
__device__ __forceinline__ float b2f(unsigned short h) {
  unsigned int u = ((unsigned int)h) << 16;
  return __builtin_bit_cast(float, u);
}

// ------- prep (grid-stride): converts + bias packing + rowsum zero -------
__global__ __launch_bounds__(256) void prep_kernel(
    const float* __restrict__ x,
    const float* __restrict__ Wq, const float* __restrict__ Wk,
    const float* __restrict__ Wv, const float* __restrict__ Wo,
    const float* __restrict__ bq, const float* __restrict__ bk,
    const float* __restrict__ bv, const float* __restrict__ bo,
    unsigned short* __restrict__ xb, unsigned short* __restrict__ Wqkvb,
    unsigned short* __restrict__ Wob, float* __restrict__ bws,
    float* __restrict__ rows) {
  const unsigned stride = gridDim.x * 256u;
  for (unsigned i = blockIdx.x * 256u + threadIdx.x; i < 3148800u; i += stride) {
    if (i < 2097152u) {
      fl4 f = *(const fl4*)&x[(size_t)i << 2];
      us4 o;
#pragma unroll
      for (int j = 0; j < 4; ++j) o[j] = f2b(f[j]);
      *(us4*)&xb[(size_t)i << 2] = o;
    } else if (i < 3145728u) {
      const unsigned k = i - 2097152u;
      const int w = k >> 18;
      const unsigned idx = k & 262143u;
      const float* s = w == 0 ? Wq : w == 1 ? Wk : w == 2 ? Wv : Wo;
      unsigned short* d = w < 3 ? Wqkvb + (size_t)w * 1024 * 1024 : Wob;
      fl4 f = *(const fl4*)&s[(size_t)idx << 2];
      us4 o;
#pragma unroll
      for (int j = 0; j < 4; ++j) o[j] = f2b(f[j]);
      *(us4*)&d[(size_t)idx << 2] = o;
    } else if (i < 3146752u) {
      const unsigned j = i - 3145728u;
      const int sel = j >> 8;
      const unsigned within = j & 255u;
      const float* p = sel == 0 ? bq : sel == 1 ? bk : sel == 2 ? bv : bo;
      *(fl4*)&bws[(size_t)j << 2] = *(const fl4*)&p[(size_t)within << 2];
    } else {
      const unsigned j = i - 3146752u;
      *(fl4*)&rows[(size_t)j << 2] = fl4{0.f, 0.f, 0.f, 0.f};
    }
  }
}

#define RD_A(dst, basep)                                                   \
  _Pragma("unroll") for (int mi = 0; mi < 4; ++mi)                         \
  _Pragma("unroll") for (int ks = 0; ks < 2; ++ks)                         \
      dst[mi][ks] = *(const short8*)((basep) + offA[mi][ks]);

#define RD_B(dst, basep)                                                   \
  _Pragma("unroll") for (int nj = 0; nj < 2; ++nj)                         \
  _Pragma("unroll") for (int ks = 0; ks < 2; ++ks)                         \
      dst[nj][ks] = *(const short8*)((basep) + offB[nj][ks]);

#define MFMA16(AF, BF, MI0, NJ0)                                           \
  __builtin_amdgcn_s_setprio(1);                                           \
  _Pragma("unroll") for (int ks = 0; ks < 2; ++ks)                         \
  _Pragma("unroll") for (int mi = 0; mi < 4; ++mi)                         \
  _Pragma("unroll") for (int nj = 0; nj < 2; ++nj)                         \
      acc[(MI0) + mi][(NJ0) + nj] = __builtin_amdgcn_mfma_f32_16x16x32_bf16( \
          AF[mi][ks], BF[nj][ks], acc[(MI0) + mi][(NJ0) + nj], 0, 0, 0);   \
  __builtin_amdgcn_s_setprio(0);

// Deep-staged 8-barrier K-loop (T4: +2-tile stage lead, one vmcnt(8)/tile).
#define KLOOP_BODY                                                         \
  stA(0, 0, 0); stB(0, 0, 0); stA(0, 1, 0); stB(0, 1, 0);                  \
  stA(1, 0, 1); stB(1, 0, 1); stA(1, 1, 1); stB(1, 1, 1);                  \
  asm volatile("s_waitcnt vmcnt(8)" ::: "memory");                         \
  __builtin_amdgcn_s_barrier();                                            \
  for (int t = 0; t < nt; ++t) {                                           \
    const int buf = t & 1;                                                 \
    const char* Ab0 = (const char*)&lA[buf][0][0];                         \
    const char* Ab1 = (const char*)&lA[buf][1][0];                         \
    const char* Bb0 = (const char*)&lB[buf][0][0];                         \
    const char* Bb1 = (const char*)&lB[buf][1][0];                         \
    short8 a0[4][2], a1[4][2], b0[2][2], b1[2][2];                         \
    RD_A(a0, Ab0);                                                         \
    RD_B(b0, Bb0);                                                         \
    __builtin_amdgcn_s_barrier();                                          \
    MFMA16(a0, b0, 0, 0);                                                  \
    __builtin_amdgcn_s_barrier();                                          \
    RD_A(a1, Ab1);                                                         \
    stA(buf, 0, t + 2);                                                    \
    stB(buf, 0, t + 2);                                                    \
    __builtin_amdgcn_s_barrier();                                          \
    MFMA16(a1, b0, 4, 0);                                                  \
    __builtin_amdgcn_s_barrier();                                          \
    RD_B(b1, Bb1);                                                         \
    stA(buf, 1, t + 2);                                                    \
    __builtin_amdgcn_s_barrier();                                          \
    MFMA16(a1, b1, 4, 2);                                                  \
    __builtin_amdgcn_s_barrier();                                          \
    stB(buf, 1, t + 2);                                                    \
    asm volatile("s_waitcnt vmcnt(8)" ::: "memory");                       \
    __builtin_amdgcn_s_barrier();                                          \
    MFMA16(a0, b1, 0, 2);                                                  \
    __builtin_amdgcn_s_barrier();                                          \
  }                                                                        \
  asm volatile("s_waitcnt vmcnt(0)" ::: "memory");

// ---------------- gemm8: 256x256 deep-staged pipelined ----------------
// EPI: 3 = bf16 + bias[col]   5 = split-K2 bf16 partial (half -> P0|P1)
//      6 = scores: bf16 exp(v*scale) causal-masked + rowsum atomics
template<int EPI, bool SPLIT2, bool SKIP_UPPER>
__global__ __launch_bounds__(512, 2)
void gemm8(const unsigned short* __restrict__ A, const unsigned short* __restrict__ B,
           void* __restrict__ Cout, const float* __restrict__ bias,
           float* __restrict__ rows, float scale, int K,
           int lda, int ldb, int ldc,
           long long sAz, long long sBz, long long sCz)
{
  const int gx = gridDim.x;
  const int nwg = gx * gridDim.y;
  int flat = blockIdx.y * gx + blockIdx.x;
  { const int q = nwg >> 3, r = nwg & 7, xc = flat & 7, i = flat >> 3;
    flat = (xc < r ? xc * (q + 1) : r * (q + 1) + (xc - r) * q) + i; }
  const int m0 = (flat / gx) << 8;
  const int n0 = (flat % gx) << 8;
  if (SKIP_UPPER && n0 > m0 + 255) return;   // fully-masked score block
  const int zraw = blockIdx.z;
  const int z = SPLIT2 ? (zraw >> 1) : zraw;

  int kBeg = 0, kEnd = K;
  if (SPLIT2) {                        // balanced causal half (PV)
    const int kFull = m0 + 256;
    const int kMid = kFull >> 1;
    kBeg = (zraw & 1) ? kMid : 0;
    kEnd = (zraw & 1) ? kFull : kMid;
  }
  const int nt = (kEnd - kBeg) >> 6;

  __shared__ unsigned short lA[2][2][8192];
  __shared__ unsigned short lB[2][2][8192];

  const int tid = threadIdx.x, lane = tid & 63, wid = tid >> 6;
  const int wm = wid >> 2, wn = wid & 3;
  const int fr = lane & 15, kg = lane >> 4;

  const unsigned short* Ab = A + (size_t)z * sAz;
  const unsigned short* Bb = B + (size_t)z * sBz;

  const int xorv = (fr & 7) << 4;
  int offA[4][2], offB[2][2];
#pragma unroll
  for (int mi = 0; mi < 4; ++mi)
#pragma unroll
    for (int ks = 0; ks < 2; ++ks)
      offA[mi][ks] = ((wm << 6) + (mi << 4) + fr) * 128 + (((ks << 6) + (kg << 4)) ^ xorv);
#pragma unroll
  for (int nj = 0; nj < 2; ++nj)
#pragma unroll
    for (int ks = 0; ks < 2; ++ks)
      offB[nj][ks] = ((wn << 5) + (nj << 4) + fr) * 128 + (((ks << 6) + (kg << 4)) ^ xorv);

  const int srow = tid >> 3;
  const int scol = (((tid & 7) ^ (srow & 7)) << 3);
  const unsigned short* aS = Ab + (size_t)(m0 + srow) * lda + scol + kBeg;
  const unsigned short* bS = Bb + (size_t)(n0 + srow) * ldb + scol + kBeg;

  auto stA = [&](int buf, int h, int tt) {
    int ttc = tt < nt ? tt : nt - 1;
    const unsigned short* s0 = aS + (size_t)(h << 7) * lda + (ttc << 6);
#pragma unroll
    for (int c = 0; c < 2; ++c)
      __builtin_amdgcn_global_load_lds(
          (const __attribute__((address_space(1))) void*)(s0 + (size_t)(c << 6) * lda),
          (__attribute__((address_space(3))) void*)((char*)&lA[buf][h][0] + (c << 13) + (tid << 4)),
          16, 0, 0);
  };
  auto stB = [&](int buf, int h, int tt) {
    int ttc = tt < nt ? tt : nt - 1;
    const unsigned short* s0 = bS + (size_t)(h << 7) * ldb + (ttc << 6);
#pragma unroll
    for (int c = 0; c < 2; ++c)
      __builtin_amdgcn_global_load_lds(
          (const __attribute__((address_space(1))) void*)(s0 + (size_t)(c << 6) * ldb),
          (__attribute__((address_space(3))) void*)((char*)&lB[buf][h][0] + (c << 13) + (tid << 4)),
          16, 0, 0);
  };

  f32x4 acc[8][4];
#pragma unroll
  for (int i = 0; i < 8; ++i)
#pragma unroll
    for (int j = 0; j < 4; ++j) acc[i][j] = f32x4{0.f, 0.f, 0.f, 0.f};

  KLOOP_BODY

  if (EPI == 6) {
    unsigned short* Ch = (unsigned short*)Cout + (size_t)z * sCz;
#pragma unroll
    for (int mig = 0; mig < 8; ++mig) {
      const int row = m0 + (mig >> 2) * 128 + wm * 64 + (mig & 3) * 16 + (kg << 2);
#pragma unroll
      for (int jj = 0; jj < 4; ++jj) {
        const int r = row + jj;
        float rs = 0.f;
#pragma unroll
        for (int njg = 0; njg < 4; ++njg) {
          const int col = n0 + (njg >> 1) * 128 + wn * 32 + (njg & 1) * 16 + fr;
          const float ee = (col <= r) ? __expf(acc[mig][njg][jj] * scale) : 0.f;
          rs += ee;
          Ch[(size_t)r * ldc + col] = f2b(ee);
        }
#pragma unroll
        for (int mk = 1; mk <= 8; mk <<= 1) rs += __shfl_xor(rs, mk, 64);
        if (fr == 0) atomicAdd(&rows[z * 2048 + r], rs);
      }
    }
    return;
  }
#pragma unroll
  for (int mig = 0; mig < 8; ++mig)
#pragma unroll
    for (int njg = 0; njg < 4; ++njg) {
      const int row = m0 + (mig >> 2) * 128 + wm * 64 + (mig & 3) * 16 + (kg << 2);
      const int col = n0 + (njg >> 1) * 128 + wn * 32 + (njg & 1) * 16 + fr;
      f32x4 v = acc[mig][njg];
      if (EPI == 3) {
        unsigned short* Ch = (unsigned short*)Cout;
        const float bb = bias[col];
#pragma unroll
        for (int jj = 0; jj < 4; ++jj)
          Ch[(size_t)(row + jj) * ldc + col] = f2b(v[jj] + bb);
      } else {   // EPI == 5: split-K2 partial; half selects P0|P1
        unsigned short* Ch = (unsigned short*)Cout +
            (size_t)(zraw & 1) * 8388608 + (size_t)z * sCz;
#pragma unroll
        for (int jj = 0; jj < 4; ++jj)
          Ch[(size_t)(row + jj) * ldc + col] = f2b(v[jj]);
      }
    }
}

// ---------------- gemm2ph: 256x128 2-phase, 4-barrier ----------------
// EPI: 2 = f32 + bias[col] (out-proj)   4 = bf16 + bias[row] (Vt-proj)
template<int EPI>
__global__ __launch_bounds__(512, 2)
void gemm2ph(const unsigned short* __restrict__ A, const unsigned short* __restrict__ B,
             void* __restrict__ Cout, const float* __restrict__ bias,
             int K, int lda, int ldb, int ldc)
{
  const int gx = gridDim.x;
  const int nwg = gx * gridDim.y;
  int flat = blockIdx.y * gx + blockIdx.x;
  { const int q = nwg >> 3, r = nwg & 7, xc = flat & 7, i = flat >> 3;
    flat = (xc < r ? xc * (q + 1) : r * (q + 1) + (xc - r) * q) + i; }
  const int m0 = (flat / gx) << 8;
  const int n0 = (flat % gx) << 7;
  const int nt = K >> 6;

  __shared__ unsigned short lA[2][2][8192];   // 64 KB
  __shared__ unsigned short lB[2][8192];      // 32 KB

  const int tid = threadIdx.x, lane = tid & 63, wid = tid >> 6;
  const int wm = wid >> 2, wn = wid & 3;
  const int fr = lane & 15, kg = lane >> 4;

  const int xorv = (fr & 7) << 4;
  int offA[4][2], offB[2][2];
#pragma unroll
  for (int mi = 0; mi < 4; ++mi)
#pragma unroll
    for (int ks = 0; ks < 2; ++ks)
      offA[mi][ks] = ((wm << 6) + (mi << 4) + fr) * 128 + (((ks << 6) + (kg << 4)) ^ xorv);
#pragma unroll
  for (int nj = 0; nj < 2; ++nj)
#pragma unroll
    for (int ks = 0; ks < 2; ++ks)
      offB[nj][ks] = ((wn << 5) + (nj << 4) + fr) * 128 + (((ks << 6) + (kg << 4)) ^ xorv);

  const int srow = tid >> 3;
  const int scol = (((tid & 7) ^ (srow & 7)) << 3);
  const unsigned short* aS = A + (size_t)(m0 + srow) * lda + scol;
  const unsigned short* bS = B + (size_t)(n0 + srow) * ldb + scol;

  auto stA = [&](int buf, int h, int tt) {
    int ttc = tt < nt ? tt : nt - 1;
    const unsigned short* s0 = aS + (size_t)(h << 7) * lda + (ttc << 6);
#pragma unroll
    for (int c = 0; c < 2; ++c)
      __builtin_amdgcn_global_load_lds(
          (const __attribute__((address_space(1))) void*)(s0 + (size_t)(c << 6) * lda),
          (__attribute__((address_space(3))) void*)((char*)&lA[buf][h][0] + (c << 13) + (tid << 4)),
          16, 0, 0);
  };
  auto stB = [&](int buf, int tt) {
    int ttc = tt < nt ? tt : nt - 1;
    const unsigned short* s0 = bS + (ttc << 6);
#pragma unroll
    for (int c = 0; c < 2; ++c)
      __builtin_amdgcn_global_load_lds(
          (const __attribute__((address_space(1))) void*)(s0 + (size_t)(c << 6) * ldb),
          (__attribute__((address_space(3))) void*)((char*)&lB[buf][0] + (c << 13) + (tid << 4)),
          16, 0, 0);
  };

  f32x4 acc[8][2];
#pragma unroll
  for (int i = 0; i < 8; ++i)
#pragma unroll
    for (int j = 0; j < 2; ++j) acc[i][j] = f32x4{0.f, 0.f, 0.f, 0.f};

  stB(0, 0); stA(0, 0, 0); stA(0, 1, 0);
  asm volatile("s_waitcnt vmcnt(2)" ::: "memory");
  __builtin_amdgcn_s_barrier();

  for (int t = 0; t < nt; ++t) {
    const int buf = t & 1, nbuf = buf ^ 1;
    const char* Ab0 = (const char*)&lA[buf][0][0];
    const char* Ab1 = (const char*)&lA[buf][1][0];
    const char* Bbp = (const char*)&lB[buf][0];

    short8 a0[4][2], a1[4][2], b0[2][2];

    RD_A(a0, Ab0);
    RD_B(b0, Bbp);
    stB(nbuf, t + 1); stA(nbuf, 0, t + 1);
    asm volatile("s_waitcnt vmcnt(4)" ::: "memory");
    __builtin_amdgcn_s_barrier();
    MFMA16(a0, b0, 0, 0);
    __builtin_amdgcn_s_barrier();

    RD_A(a1, Ab1);
    stA(nbuf, 1, t + 1);
    asm volatile("s_waitcnt vmcnt(2)" ::: "memory");
    __builtin_amdgcn_s_barrier();
    MFMA16(a1, b0, 4, 0);
    __builtin_amdgcn_s_barrier();
  }
  asm volatile("s_waitcnt vmcnt(0)" ::: "memory");

#pragma unroll
  for (int mig = 0; mig < 8; ++mig)
#pragma unroll
    for (int njg = 0; njg < 2; ++njg) {
      const int row = m0 + (mig >> 2) * 128 + wm * 64 + (mig & 3) * 16 + (kg << 2);
      const int col = n0 + wn * 32 + njg * 16 + fr;
      f32x4 v = acc[mig][njg];
      if (EPI == 2) {
        float* Cf = (float*)Cout;
        const float bb = bias[col];
#pragma unroll
        for (int jj = 0; jj < 4; ++jj)
          Cf[(size_t)(row + jj) * ldc + col] = v[jj] + bb;
      } else {   // EPI == 4: bias by row (Vt-proj)
        unsigned short* Ch = (unsigned short*)Cout;
#pragma unroll
        for (int jj = 0; jj < 4; ++jj)
          Ch[(size_t)(row + jj) * ldc + col] = f2b(v[jj] + bias[row + jj]);
      }
    }
}

// ---- split-K2 reduce + normalize (grid-stride): attn = (P0+P1)/rowsum ----
__global__ __launch_bounds__(256)
void reduce_pv2(const unsigned short* __restrict__ p0,
                const unsigned short* __restrict__ p1,
                const float* __restrict__ rows,
                unsigned short* __restrict__ out) {
  const unsigned stride = gridDim.x * 256u;
  for (unsigned g = blockIdx.x * 256u + threadIdx.x; g < 1048576u; g += stride) {
    const size_t i = (size_t)g << 3;
    const float inv = 1.f / rows[i >> 10];
    us8 a = *(const us8*)&p0[i];
    us8 b = *(const us8*)&p1[i];
    us8 o;
#pragma unroll
    for (int j = 0; j < 8; ++j)
      o[j] = f2b((b2f(a[j]) + b2f(b[j])) * inv);
    *(us8*)&out[i] = o;
  }
}

// ---------------- host-side launch ----------------
extern "C" void kernel_launch(void* const* d_in, const int* in_sizes, int n_in,
                              void* d_out, int out_size, void* d_ws, size_t ws_size,
                              hipStream_t stream) {
  (void)in_sizes; (void)n_in; (void)out_size; (void)ws_size;
  const float* x  = (const float*)d_in[0];
  const float* Wq = (const float*)d_in[1];
  const float* bq = (const float*)d_in[2];
  const float* Wk = (const float*)d_in[3];
  const float* bk = (const float*)d_in[4];
  const float* Wv = (const float*)d_in[5];
  const float* bv = (const float*)d_in[6];
  const float* Wo = (const float*)d_in[7];
  const float* bo = (const float*)d_in[8];

  const int B = 4, T = 2048, C = 1024;
  const int M = B * T;                                   // 8192

  unsigned short* xb    = (unsigned short*)d_ws;         // M*C
  unsigned short* Wqkvb = xb    + (size_t)M * C;         // [Wq|Wk|Wv]
  unsigned short* Wob   = Wqkvb + (size_t)3 * C * C;
  unsigned short* QK    = Wob   + (size_t)C * C;         // M*2C [Q|K]; later P0|P1
  unsigned short* Vt    = QK    + (size_t)M * 2 * C;     // [1024][8192]
  unsigned short* S     = Vt    + (size_t)M * C;         // B*T*T e-values
  float*          bws   = (float*)(S + (size_t)B * T * T);
  float*          rowsum= bws + 4096;                    // 8192 f32
  unsigned short* P0    = QK;
  unsigned short* P1    = QK + (size_t)M * C;
  unsigned short* attn  = P0;

  // 1. prep (grid-stride, 2048 blocks)
  prep_kernel<<<2048, 256, 0, stream>>>(x, Wq, Wk, Wv, Wo, bq, bk, bv, bo,
                                        xb, Wqkvb, Wob, bws, rowsum);

  // 2. QK projection (256 blocks)
  gemm8<3, false, false><<<dim3(2 * C / 256, M / 256, 1), 512, 0, stream>>>(
      xb, Wqkvb, QK, bws, nullptr, 1.f, C, C, C, 2 * C, 0LL, 0LL, 0LL);

  // 3. Vt = Wv @ x^T + bv[row] (256 blocks, BN=128)
  gemm2ph<4><<<dim3(M / 128, C / 256, 1), 512, 0, stream>>>(
      Wqkvb + (size_t)2 * C * C, xb, Vt, bws + 2 * C, C, C, C, M);

  // 4. scores: S = exp(Q K^T / 32) causal-masked + rowsum atomics
  gemm8<6, false, true><<<dim3(T / 256, T / 256, B), 512, 0, stream>>>(
      QK, QK + C, S, nullptr, rowsum, 0.03125f, C, 2 * C, 2 * C, T,
      (long long)T * 2 * C, (long long)T * 2 * C, (long long)T * T);

  // 5. PV split-K2: partials P0|P1 (z = batch*2 + half), 256 blocks
  gemm8<5, true, false><<<dim3(C / 256, T / 256, 2 * B), 512, 0, stream>>>(
      S, Vt, P0, nullptr, nullptr, 1.f, T, T, M, C,
      (long long)T * T, 2048LL, (long long)T * C);

  // 6. reduce + normalize (grid-stride, 2048 blocks; attn -> P0 in place)
  reduce_pv2<<<2048, 256, 0, stream>>>(P0, P1, rowsum, attn);

  // 7. out = attn Wo^T + bo (f32, 256 blocks BN=128)
  gemm2ph<2><<<dim3(C / 128, M / 256, 1), 512, 0, stream>>>(
      attn, Wob, d_out, bws + 3 * C, C, C, C, C);
}